// Round 7
// baseline (186.509 us; speedup 1.0000x reference)
//
#include <hip/hip_runtime.h>
#include <hip/hip_bf16.h>

constexpr int NB  = 2;
constexpr int SL  = 2048;
constexpr int EMB = 1024;
constexpr int NH  = 16;
constexpr int HD  = 64;
constexpr int MT  = NB * SL;               // 4096 rows for projection GEMMs
constexpr size_t PROJ = (size_t)MT * EMB;  // 4M elements per [N,L,E] buffer

typedef __attribute__((ext_vector_type(8))) short bf16x8;  // 8 bf16 (4 VGPRs)
typedef __attribute__((ext_vector_type(4))) float f32x4;   // MFMA C/D frag

__device__ inline short f2b(float f) {
  __hip_bfloat16 b = __float2bfloat16(f);
  short s; __builtin_memcpy(&s, &b, 2); return s;
}

#define GLDS16(g, l)                                                     \
  __builtin_amdgcn_global_load_lds(                                      \
      (const __attribute__((address_space(1))) void*)(g),                \
      (__attribute__((address_space(3))) void*)(l), 16, 0, 0)

// ---------------------------------------------------------------------------
// Cast fp32 -> bf16: x -> xb, {Wq,Wk,Wv} -> wqkv (concat rows), Wo -> wob.
// ---------------------------------------------------------------------------
__global__ __launch_bounds__(256) void cast_all(
    const float* __restrict__ x,  const float* __restrict__ wq,
    const float* __restrict__ wk, const float* __restrict__ wv,
    const float* __restrict__ wo, short* __restrict__ xb,
    short* __restrict__ wqkv, short* __restrict__ wob) {
  const size_t t = (size_t)blockIdx.x * 256 + threadIdx.x;  // float4 index
  const float* src; short* dst; size_t base;
  if (t < 1048576)      { src = x;  dst = xb;              base = 0; }
  else if (t < 1310720) { src = wq; dst = wqkv;            base = 1048576; }
  else if (t < 1572864) { src = wk; dst = wqkv + (1 << 20); base = 1310720; }
  else if (t < 1835008) { src = wv; dst = wqkv + (2 << 20); base = 1572864; }
  else                  { src = wo; dst = wob;             base = 1835008; }
  const size_t i = t - base;
  const float4 v = ((const float4*)src)[i];
  const short4 o = {f2b(v.x), f2b(v.y), f2b(v.z), f2b(v.w)};
  ((short4*)dst)[i] = o;
}

// ---------------------------------------------------------------------------
// QKV GEMM (m97 recipe): C = x[4096][1024] @ wqkv[3072][1024]^T.
// 128x128 tile, BK=32, global_load_lds w16. Epilogue per n-region:
//   0 -> Q * (log2e/32)  (exp2 + score-scale folded)   bf16 natural
//   1 -> K                                             bf16 natural
//   2 -> V^T [nb][h][d][seq'] , seq' = 32-block key permutation
//        pos = 8*((k>>2)&3) + 4*(k>>4) + (k&3)  (attn PV A-frag order)
// ---------------------------------------------------------------------------
__global__ __launch_bounds__(256) void gemm_qkv(
    const short* __restrict__ A, const short* __restrict__ W,
    short* __restrict__ qb, short* __restrict__ kb, short* __restrict__ vt) {
  __shared__ short As[128 * 32];
  __shared__ short Bs[128 * 32];
  const int tid = threadIdx.x;
  const int w = tid >> 6, lane = tid & 63;
  const int la = lane >> 4, lb = lane & 15;
  const int wm = w & 1, wn = w >> 1;
  const int m0 = blockIdx.y << 7, n0 = blockIdx.x << 7;
  const int srow = lane >> 2, scol = (lane & 3) << 3;
  const short* a0 = A + (size_t)(m0 + w * 16 + srow) * 1024 + scol;
  const short* b0 = W + (size_t)(n0 + w * 16 + srow) * 1024 + scol;
  short* lA0 = As + (w * 16) * 32;
  short* lA1 = As + (64 + w * 16) * 32;
  short* lB0 = Bs + (w * 16) * 32;
  short* lB1 = Bs + (64 + w * 16) * 32;

  f32x4 acc[4][4];
#pragma unroll
  for (int i = 0; i < 4; ++i)
#pragma unroll
    for (int j = 0; j < 4; ++j) acc[i][j] = (f32x4){0.f, 0.f, 0.f, 0.f};

  for (int k0 = 0; k0 < 1024; k0 += 32) {
    __syncthreads();
    GLDS16(a0 + k0, lA0);
    GLDS16(a0 + 64 * 1024 + k0, lA1);
    GLDS16(b0 + k0, lB0);
    GLDS16(b0 + 64 * 1024 + k0, lB1);
    __syncthreads();
    bf16x8 af[4], bf[4];
#pragma unroll
    for (int i = 0; i < 4; ++i)
      af[i] = *(const bf16x8*)&As[(wm * 64 + i * 16 + lb) * 32 + la * 8];
#pragma unroll
    for (int j = 0; j < 4; ++j)
      bf[j] = *(const bf16x8*)&Bs[(wn * 64 + j * 16 + lb) * 32 + la * 8];
#pragma unroll
    for (int i = 0; i < 4; ++i)
#pragma unroll
      for (int j = 0; j < 4; ++j)
        acc[i][j] = __builtin_amdgcn_mfma_f32_16x16x32_bf16(af[i], bf[j],
                                                            acc[i][j], 0, 0, 0);
  }

  const int region = n0 >> 10;  // block-uniform (n-tile 128 < 1024)
  if (region < 2) {
    short* dst = region ? kb : qb;
    const float sc = region ? 1.0f : 0.03125f * 1.44269504f;  // Q: 1/32*log2e
    const int nb0 = n0 & 1023;
#pragma unroll
    for (int j = 0; j < 4; ++j) {
      const int nj = nb0 + wn * 64 + j * 16 + lb;
#pragma unroll
      for (int i = 0; i < 4; ++i) {
        const int mi = m0 + wm * 64 + i * 16 + la * 4;
#pragma unroll
        for (int r = 0; r < 4; ++r)
          dst[(size_t)(mi + r) * 1024 + nj] = f2b(acc[i][j][r] * sc);
      }
    }
  } else {
#pragma unroll
    for (int j = 0; j < 4; ++j) {
      const int nv = (n0 - 2048) + wn * 64 + j * 16 + lb;
      const int h = nv >> 6, d = nv & 63;
#pragma unroll
      for (int i = 0; i < 4; ++i) {
        const int mi = m0 + wm * 64 + i * 16 + la * 4;
        const int nbi = mi >> 11, seq = mi & (SL - 1);
        const int k5 = seq & 31;  // multiple of 4
        const int seqp = (seq & ~31) | (8 * ((k5 >> 2) & 3) + 4 * (k5 >> 4));
        const short4 o = {f2b(acc[i][j][0]), f2b(acc[i][j][1]),
                          f2b(acc[i][j][2]), f2b(acc[i][j][3])};
        *(short4*)&vt[((size_t)(nbi * NH + h) * HD + d) * SL + seqp] = o;
      }
    }
  }
}

// ---------------------------------------------------------------------------
// Out GEMM: out = ab[4096][1024](bf16) @ wob[1024][1024]^T + bias, fp32 out.
// 128m x 64n tile -> 512 blocks (2/CU) so barrier drains overlap.
// ---------------------------------------------------------------------------
__global__ __launch_bounds__(256) void gemm_out(
    const short* __restrict__ A, const short* __restrict__ W,
    const float* __restrict__ bias, float* __restrict__ out) {
  __shared__ short As[128 * 32];
  __shared__ short Bs[64 * 32];
  const int tid = threadIdx.x;
  const int w = tid >> 6, lane = tid & 63;
  const int la = lane >> 4, lb = lane & 15;
  const int wm = w & 1, wn = w >> 1;
  const int m0 = blockIdx.y << 7, n0 = blockIdx.x << 6;
  const int srow = lane >> 2, scol = (lane & 3) << 3;
  const short* a0 = A + (size_t)(m0 + w * 16 + srow) * 1024 + scol;
  const short* b0 = W + (size_t)(n0 + w * 16 + srow) * 1024 + scol;
  short* lA0 = As + (w * 16) * 32;
  short* lA1 = As + (64 + w * 16) * 32;
  short* lB0 = Bs + (w * 16) * 32;

  f32x4 acc[4][2];
#pragma unroll
  for (int i = 0; i < 4; ++i)
#pragma unroll
    for (int j = 0; j < 2; ++j) acc[i][j] = (f32x4){0.f, 0.f, 0.f, 0.f};

  for (int k0 = 0; k0 < 1024; k0 += 32) {
    __syncthreads();
    GLDS16(a0 + k0, lA0);
    GLDS16(a0 + 64 * 1024 + k0, lA1);
    GLDS16(b0 + k0, lB0);
    __syncthreads();
    bf16x8 af[4], bf[2];
#pragma unroll
    for (int i = 0; i < 4; ++i)
      af[i] = *(const bf16x8*)&As[(wm * 64 + i * 16 + lb) * 32 + la * 8];
#pragma unroll
    for (int j = 0; j < 2; ++j)
      bf[j] = *(const bf16x8*)&Bs[(wn * 32 + j * 16 + lb) * 32 + la * 8];
#pragma unroll
    for (int i = 0; i < 4; ++i)
#pragma unroll
      for (int j = 0; j < 2; ++j)
        acc[i][j] = __builtin_amdgcn_mfma_f32_16x16x32_bf16(af[i], bf[j],
                                                            acc[i][j], 0, 0, 0);
  }
#pragma unroll
  for (int j = 0; j < 2; ++j) {
    const int nj = n0 + wn * 32 + j * 16 + lb;
    const float bv = bias[nj];
#pragma unroll
    for (int i = 0; i < 4; ++i) {
      const int mi = m0 + wm * 64 + i * 16 + la * 4;
#pragma unroll
      for (int r = 0; r < 4; ++r)
        out[(size_t)(mi + r) * 1024 + nj] = acc[i][j][r] + bv;
    }
  }
}

// ---------------------------------------------------------------------------
// Flash attention v5: 128q block, 2x2 wave grid (wq = q-half of 64q,
// wk = key-half of 32 keys per 64-key tile).
//  * K/V staged FRAGMENT-MAJOR via global_load_lds: frag f of tile lives at
//    mem[(buf*16+f)*512 + lane*8] — exactly GLDS's wave-uniform-base +
//    lane*16B deposit, so ALL LDS reads/writes are lane-linear (0 conflicts),
//    and staging never touches VGPRs.
//  * Double-buffered, ONE barrier per iter: issue tile kt+1 after the
//    barrier, compute kt; the vmcnt drain at the next barrier finds the
//    loads already landed (overlapped with compute).
//  * Q fragments loaded once, straight from global to registers (no LDS).
//  * P = exp2(S) stays in C-regs -> PV B-operand (V pre-permuted per
//    32-key block in global, window = 32*wk).
//  * l shuffles deferred to epilogue; 2-way cross-wave O reduction (wk).
// Frag ids: K(kb2,ks) = 2*kb2+ks (0..7), V(mtd,w2) = 8+2*mtd+w2 (8..15).
// Wave w issues frags 4w..4w+3. LDS ~35 KB.
// ---------------------------------------------------------------------------
__global__ __launch_bounds__(256, 2) void attn_mfma(const short* __restrict__ Qg,
                                                    const short* __restrict__ Kg,
                                                    const short* __restrict__ Vtg,
                                                    short* __restrict__ Ab) {
  __shared__ __align__(16) short mem[17408];  // 32KB staging / 34.8KB reduction
  __shared__ float lred[128];
  const int tid = threadIdx.x;
  const int w = tid >> 6, lane = tid & 63;
  const int G = lane >> 4, lb = lane & 15;
  const int wk = w & 1, wq = w >> 1;
  const int qt = blockIdx.x, h = blockIdx.y, n = blockIdx.z;

  // ---- staging plan: wave w issues frags 4w..4w+3 each iter
  const bool isK = (w < 2);
  const short* gbase = isK ? (Kg + ((size_t)(n * SL)) * EMB + h * HD)
                           : (Vtg + ((size_t)(n * NH + h)) * HD * SL);
  const size_t gstep = isK ? (size_t)64 * EMB : (size_t)64;
  size_t go[4];
#pragma unroll
  for (int i = 0; i < 4; ++i) {
    if (isK) {  // kb2 = 2w + (i>>1), ks = i&1
      go[i] = (size_t)(16 * (2 * w + (i >> 1)) + lb) * EMB + 32 * (i & 1) + 8 * G;
    } else {    // mtd = 2(w-2) + (i>>1), w2 = i&1
      go[i] = (size_t)(16 * (2 * (w - 2) + (i >> 1)) + lb) * SL + 32 * (i & 1) + 8 * G;
    }
  }

  // ---- Q fragments: global -> regs, once. q = 64wq + 16nt + lb, d = 32ks+8G
  const short* Qb = Qg + ((size_t)(n * SL + (qt << 7) + 64 * wq)) * EMB + h * HD;
  bf16x8 bQ[4][2];
#pragma unroll
  for (int nt = 0; nt < 4; ++nt)
#pragma unroll
    for (int ks = 0; ks < 2; ++ks)
      bQ[nt][ks] = *(const bf16x8*)(Qb + (size_t)(16 * nt + lb) * EMB + 32 * ks + 8 * G);

  // preload tile 0 into buf 0
#pragma unroll
  for (int i = 0; i < 4; ++i) GLDS16(gbase + go[i], &mem[(4 * w + i) * 512]);

  f32x4 O[4][4];  // [mtd: d=16mtd+4G+r][nt: q=64wq+16nt+lb]
  float lacc[4] = {0.f, 0.f, 0.f, 0.f};
#pragma unroll
  for (int i = 0; i < 4; ++i)
#pragma unroll
    for (int j = 0; j < 4; ++j) O[i][j] = (f32x4){0.f, 0.f, 0.f, 0.f};

  for (int kt = 0; kt < SL / 64; ++kt) {
    __syncthreads();  // drains tile-kt GLDS; closes prev reads of other buf
    if (kt + 1 < SL / 64) {
      const short* g = gbase + (size_t)(kt + 1) * gstep;
      const int b = (kt + 1) & 1;
#pragma unroll
      for (int i = 0; i < 4; ++i)
        GLDS16(g + go[i], &mem[(b * 16 + 4 * w + i) * 512]);
    }
    const int c = (kt & 1) * 8192;

    // ---- S^T = K Q^T over this wave's 32-key half (frags 4wk + 2mt + ks)
    f32x4 S[2][4];
#pragma unroll
    for (int mt = 0; mt < 2; ++mt)
#pragma unroll
      for (int nt = 0; nt < 4; ++nt) S[mt][nt] = (f32x4){0.f, 0.f, 0.f, 0.f};
#pragma unroll
    for (int ks = 0; ks < 2; ++ks) {
      const bf16x8 aK0 = *(const bf16x8*)&mem[c + (4 * wk + ks) * 512 + lane * 8];
      const bf16x8 aK1 = *(const bf16x8*)&mem[c + (4 * wk + 2 + ks) * 512 + lane * 8];
#pragma unroll
      for (int nt = 0; nt < 4; ++nt) {
        S[0][nt] = __builtin_amdgcn_mfma_f32_16x16x32_bf16(aK0, bQ[nt][ks],
                                                           S[0][nt], 0, 0, 0);
        S[1][nt] = __builtin_amdgcn_mfma_f32_16x16x32_bf16(aK1, bQ[nt][ks],
                                                           S[1][nt], 0, 0, 0);
      }
    }

    // ---- P = exp2(S) in-regs; lane-local l (cross-lane deferred to end)
#pragma unroll
    for (int nt = 0; nt < 4; ++nt)
#pragma unroll
      for (int mt = 0; mt < 2; ++mt)
#pragma unroll
        for (int r = 0; r < 4; ++r) {
          const float p = __builtin_amdgcn_exp2f(S[mt][nt][r]);
          S[mt][nt][r] = p;
          lacc[nt] += p;
        }

    // ---- O^T += V_perm P : A = V frags (8 + 2mtd + wk), B = P from C-regs
    bf16x8 aV[4];
#pragma unroll
    for (int mtd = 0; mtd < 4; ++mtd)
      aV[mtd] = *(const bf16x8*)&mem[c + (8 + 2 * mtd + wk) * 512 + lane * 8];
#pragma unroll
    for (int nt = 0; nt < 4; ++nt) {
      bf16x8 B2;
      B2[0] = f2b(S[0][nt][0]);
      B2[1] = f2b(S[0][nt][1]);
      B2[2] = f2b(S[0][nt][2]);
      B2[3] = f2b(S[0][nt][3]);
      B2[4] = f2b(S[1][nt][0]);
      B2[5] = f2b(S[1][nt][1]);
      B2[6] = f2b(S[1][nt][2]);
      B2[7] = f2b(S[1][nt][3]);
#pragma unroll
      for (int mtd = 0; mtd < 4; ++mtd)
        O[mtd][nt] = __builtin_amdgcn_mfma_f32_16x16x32_bf16(aV[mtd], B2,
                                                             O[mtd][nt], 0, 0, 0);
    }
  }

  // ---- finish l: reduce across G groups (sum over this wave's 32 keys)
#pragma unroll
  for (int nt = 0; nt < 4; ++nt) {
    lacc[nt] += __shfl_xor(lacc[nt], 16);
    lacc[nt] += __shfl_xor(lacc[nt], 32);
  }

  // ---- 2-way cross-wave reduction over wk; overlay red[wq][q][68] on mem
  float* red = (float*)mem;
  __syncthreads();
  if (wk == 1) {
#pragma unroll
    for (int nt = 0; nt < 4; ++nt) {
      const int q = 16 * nt + lb;
#pragma unroll
      for (int mtd = 0; mtd < 4; ++mtd)
        *(f32x4*)&red[wq * 4352 + q * 68 + 16 * mtd + 4 * G] = O[mtd][nt];
      if (G == 0) lred[wq * 64 + q] = lacc[nt];
    }
  }
  __syncthreads();
  if (wk == 0) {
    short* Ao = Ab + ((size_t)(n * SL + (qt << 7) + 64 * wq)) * EMB + h * HD;
#pragma unroll
    for (int nt = 0; nt < 4; ++nt) {
      const int q = 16 * nt + lb;
      const float inv = 1.f / (lacc[nt] + lred[wq * 64 + q]);
#pragma unroll
      for (int mtd = 0; mtd < 4; ++mtd) {
        const f32x4 t = *(const f32x4*)&red[wq * 4352 + q * 68 + 16 * mtd + 4 * G];
        const f32x4 s = t + O[mtd][nt];
        const short4 o = {f2b(s[0] * inv), f2b(s[1] * inv), f2b(s[2] * inv),
                          f2b(s[3] * inv)};
        *(short4*)(Ao + (size_t)q * EMB + 16 * mtd + 4 * G) = o;
      }
    }
  }
}

extern "C" void kernel_launch(void* const* d_in, const int* in_sizes, int n_in,
                              void* d_out, int out_size, void* d_ws, size_t ws_size,
                              hipStream_t stream) {
  const float* x  = (const float*)d_in[0];
  const float* Wq = (const float*)d_in[1];
  const float* Wk = (const float*)d_in[2];
  const float* Wv = (const float*)d_in[3];
  const float* Wo = (const float*)d_in[4];
  const float* bo = (const float*)d_in[5];
  float* out = (float*)d_out;

  // ws (bf16 elements): xb 4M | wqkv 3M | wob 1M | qb 4M | kb 4M | vt 4M = 40 MB
  short* xb   = (short*)d_ws;
  short* wqkv = xb + PROJ;
  short* wob  = wqkv + 3u * EMB * EMB;
  short* qb   = wob + (size_t)EMB * EMB;
  short* kb   = qb + PROJ;
  short* vt   = kb + PROJ;
  short* ab   = qb;  // alias: block-disjoint read-then-write regions

  cast_all<<<8192, 256, 0, stream>>>(x, Wq, Wk, Wv, Wo, xb, wqkv, wob);
  gemm_qkv<<<dim3(24, 32), 256, 0, stream>>>(xb, wqkv, qb, kb, vt);
  attn_mfma<<<dim3(SL / 128, NH, NB), 256, 0, stream>>>(qb, kb, vt, ab);
  gemm_out<<<dim3(16, 32), 256, 0, stream>>>(ab, wob, bo, out);
}

// Round 8
// 178.904 us; speedup vs baseline: 1.0425x; 1.0425x over previous
//
#include <hip/hip_runtime.h>
#include <hip/hip_bf16.h>

constexpr int NB  = 2;
constexpr int SL  = 2048;
constexpr int EMB = 1024;
constexpr int NH  = 16;
constexpr int HD  = 64;
constexpr int MT  = NB * SL;               // 4096 rows for projection GEMMs
constexpr size_t PROJ = (size_t)MT * EMB;  // 4M elements per [N,L,E] buffer

typedef __attribute__((ext_vector_type(8))) short bf16x8;  // 8 bf16 (4 VGPRs)
typedef __attribute__((ext_vector_type(4))) float f32x4;   // MFMA C/D frag

__device__ inline short f2b(float f) {
  __hip_bfloat16 b = __float2bfloat16(f);
  short s; __builtin_memcpy(&s, &b, 2); return s;
}

#define GLDS16(g, l)                                                     \
  __builtin_amdgcn_global_load_lds(                                      \
      (const __attribute__((address_space(1))) void*)(g),                \
      (__attribute__((address_space(3))) void*)(l), 16, 0, 0)

// ---------------------------------------------------------------------------
// Cast fp32 -> bf16: x -> xb, {Wq,Wk,Wv} -> wqkv (concat rows), Wo -> wob.
// ---------------------------------------------------------------------------
__global__ __launch_bounds__(256) void cast_all(
    const float* __restrict__ x,  const float* __restrict__ wq,
    const float* __restrict__ wk, const float* __restrict__ wv,
    const float* __restrict__ wo, short* __restrict__ xb,
    short* __restrict__ wqkv, short* __restrict__ wob) {
  const size_t t = (size_t)blockIdx.x * 256 + threadIdx.x;  // float4 index
  const float* src; short* dst; size_t base;
  if (t < 1048576)      { src = x;  dst = xb;              base = 0; }
  else if (t < 1310720) { src = wq; dst = wqkv;            base = 1048576; }
  else if (t < 1572864) { src = wk; dst = wqkv + (1 << 20); base = 1310720; }
  else if (t < 1835008) { src = wv; dst = wqkv + (2 << 20); base = 1572864; }
  else                  { src = wo; dst = wob;             base = 1835008; }
  const size_t i = t - base;
  const float4 v = ((const float4*)src)[i];
  const short4 o = {f2b(v.x), f2b(v.y), f2b(v.z), f2b(v.w)};
  ((short4*)dst)[i] = o;
}

// ---------------------------------------------------------------------------
// QKV GEMM (m97 recipe): C = x[4096][1024] @ wqkv[3072][1024]^T.
// 128x128 tile, BK=32, global_load_lds w16. Epilogue per n-region:
//   0 -> Q * (log2e/32)  (exp2 + score-scale folded)   bf16 natural
//   1 -> K                                             bf16 natural
//   2 -> V^T [nb][h][d][seq'] , seq' = 32-block key permutation
//        pos = 8*((k>>2)&3) + 4*(k>>4) + (k&3)  (attn PV A-frag order)
// ---------------------------------------------------------------------------
__global__ __launch_bounds__(256) void gemm_qkv(
    const short* __restrict__ A, const short* __restrict__ W,
    short* __restrict__ qb, short* __restrict__ kb, short* __restrict__ vt) {
  __shared__ short As[128 * 32];
  __shared__ short Bs[128 * 32];
  const int tid = threadIdx.x;
  const int w = tid >> 6, lane = tid & 63;
  const int la = lane >> 4, lb = lane & 15;
  const int wm = w & 1, wn = w >> 1;
  const int m0 = blockIdx.y << 7, n0 = blockIdx.x << 7;
  const int srow = lane >> 2, scol = (lane & 3) << 3;
  const short* a0 = A + (size_t)(m0 + w * 16 + srow) * 1024 + scol;
  const short* b0 = W + (size_t)(n0 + w * 16 + srow) * 1024 + scol;
  short* lA0 = As + (w * 16) * 32;
  short* lA1 = As + (64 + w * 16) * 32;
  short* lB0 = Bs + (w * 16) * 32;
  short* lB1 = Bs + (64 + w * 16) * 32;

  f32x4 acc[4][4];
#pragma unroll
  for (int i = 0; i < 4; ++i)
#pragma unroll
    for (int j = 0; j < 4; ++j) acc[i][j] = (f32x4){0.f, 0.f, 0.f, 0.f};

  for (int k0 = 0; k0 < 1024; k0 += 32) {
    __syncthreads();
    GLDS16(a0 + k0, lA0);
    GLDS16(a0 + 64 * 1024 + k0, lA1);
    GLDS16(b0 + k0, lB0);
    GLDS16(b0 + 64 * 1024 + k0, lB1);
    __syncthreads();
    bf16x8 af[4], bf[4];
#pragma unroll
    for (int i = 0; i < 4; ++i)
      af[i] = *(const bf16x8*)&As[(wm * 64 + i * 16 + lb) * 32 + la * 8];
#pragma unroll
    for (int j = 0; j < 4; ++j)
      bf[j] = *(const bf16x8*)&Bs[(wn * 64 + j * 16 + lb) * 32 + la * 8];
#pragma unroll
    for (int i = 0; i < 4; ++i)
#pragma unroll
      for (int j = 0; j < 4; ++j)
        acc[i][j] = __builtin_amdgcn_mfma_f32_16x16x32_bf16(af[i], bf[j],
                                                            acc[i][j], 0, 0, 0);
  }

  const int region = n0 >> 10;  // block-uniform (n-tile 128 < 1024)
  if (region < 2) {
    short* dst = region ? kb : qb;
    const float sc = region ? 1.0f : 0.03125f * 1.44269504f;  // Q: 1/32*log2e
    const int nb0 = n0 & 1023;
#pragma unroll
    for (int j = 0; j < 4; ++j) {
      const int nj = nb0 + wn * 64 + j * 16 + lb;
#pragma unroll
      for (int i = 0; i < 4; ++i) {
        const int mi = m0 + wm * 64 + i * 16 + la * 4;
#pragma unroll
        for (int r = 0; r < 4; ++r)
          dst[(size_t)(mi + r) * 1024 + nj] = f2b(acc[i][j][r] * sc);
      }
    }
  } else {
#pragma unroll
    for (int j = 0; j < 4; ++j) {
      const int nv = (n0 - 2048) + wn * 64 + j * 16 + lb;
      const int h = nv >> 6, d = nv & 63;
#pragma unroll
      for (int i = 0; i < 4; ++i) {
        const int mi = m0 + wm * 64 + i * 16 + la * 4;
        const int nbi = mi >> 11, seq = mi & (SL - 1);
        const int k5 = seq & 31;  // multiple of 4
        const int seqp = (seq & ~31) | (8 * ((k5 >> 2) & 3) + 4 * (k5 >> 4));
        const short4 o = {f2b(acc[i][j][0]), f2b(acc[i][j][1]),
                          f2b(acc[i][j][2]), f2b(acc[i][j][3])};
        *(short4*)&vt[((size_t)(nbi * NH + h) * HD + d) * SL + seqp] = o;
      }
    }
  }
}

// ---------------------------------------------------------------------------
// Out GEMM: out = ab[4096][1024](bf16) @ wob[1024][1024]^T + bias, fp32 out.
// 128m x 64n tile -> 512 blocks (2/CU) so barrier drains overlap.
// ---------------------------------------------------------------------------
__global__ __launch_bounds__(256) void gemm_out(
    const short* __restrict__ A, const short* __restrict__ W,
    const float* __restrict__ bias, float* __restrict__ out) {
  __shared__ short As[128 * 32];
  __shared__ short Bs[64 * 32];
  const int tid = threadIdx.x;
  const int w = tid >> 6, lane = tid & 63;
  const int la = lane >> 4, lb = lane & 15;
  const int wm = w & 1, wn = w >> 1;
  const int m0 = blockIdx.y << 7, n0 = blockIdx.x << 6;
  const int srow = lane >> 2, scol = (lane & 3) << 3;
  const short* a0 = A + (size_t)(m0 + w * 16 + srow) * 1024 + scol;
  const short* b0 = W + (size_t)(n0 + w * 16 + srow) * 1024 + scol;
  short* lA0 = As + (w * 16) * 32;
  short* lA1 = As + (64 + w * 16) * 32;
  short* lB0 = Bs + (w * 16) * 32;

  f32x4 acc[4][2];
#pragma unroll
  for (int i = 0; i < 4; ++i)
#pragma unroll
    for (int j = 0; j < 2; ++j) acc[i][j] = (f32x4){0.f, 0.f, 0.f, 0.f};

  for (int k0 = 0; k0 < 1024; k0 += 32) {
    __syncthreads();
    GLDS16(a0 + k0, lA0);
    GLDS16(a0 + 64 * 1024 + k0, lA1);
    GLDS16(b0 + k0, lB0);
    __syncthreads();
    bf16x8 af[4], bf[2];
#pragma unroll
    for (int i = 0; i < 4; ++i)
      af[i] = *(const bf16x8*)&As[(wm * 64 + i * 16 + lb) * 32 + la * 8];
#pragma unroll
    for (int j = 0; j < 2; ++j)
      bf[j] = *(const bf16x8*)&Bs[(wn * 32 + j * 16 + lb) * 32 + la * 8];
#pragma unroll
    for (int i = 0; i < 4; ++i)
#pragma unroll
      for (int j = 0; j < 2; ++j)
        acc[i][j] = __builtin_amdgcn_mfma_f32_16x16x32_bf16(af[i], bf[j],
                                                            acc[i][j], 0, 0, 0);
  }
#pragma unroll
  for (int j = 0; j < 2; ++j) {
    const int nj = n0 + wn * 32 + j * 16 + lb;
    const float bv = bias[nj];
#pragma unroll
    for (int i = 0; i < 4; ++i) {
      const int mi = m0 + wm * 64 + i * 16 + la * 4;
#pragma unroll
      for (int r = 0; r < 4; ++r)
        out[(size_t)(mi + r) * 1024 + nj] = acc[i][j][r] + bv;
    }
  }
}

// ---------------------------------------------------------------------------
// Flash attention v6 = R6 staging + R7 compute split (the hybrid):
//  * 128q block, 2x2 wave grid: wq = q-half (64q), wk = key-half (32 of 64).
//    Fragment reads: 8 b128/wave-iter (vs 16 in R6), no 4x duplication.
//  * Staging = R6's proven coalesced path: global b128 -> regs (prefetch,
//    issued right after the staging barrier so latency overlaps compute)
//    -> row-major LDS write next iter. NO gather loads (R7's mistake).
//  * Q fragments straight global -> regs, once (no Q LDS).
//  * P = exp2(S) stays in C-regs -> PV B-operand; V pre-permuted per
//    32-key block in global (window = 32*wk).
//  * l shuffles deferred to epilogue; 2-way cross-wave O reduction (wk),
//    overlaid on the staging LDS.
// LDS: max(stage 18.4KB, red 34.8KB) + lred = ~35.3KB.
// ---------------------------------------------------------------------------
__global__ __launch_bounds__(256, 2) void attn_mfma(const short* __restrict__ Qg,
                                                    const short* __restrict__ Kg,
                                                    const short* __restrict__ Vtg,
                                                    short* __restrict__ Ab) {
  __shared__ __align__(16) char smem[34816];  // stage 18432 / red 34816
  __shared__ float lred[128];
  short (*Ks)[72] = (short(*)[72])smem;                    // [64][72]
  short (*Vt)[72] = (short(*)[72])(smem + 64 * 72 * 2);    // [64][72]
  float* red = (float*)smem;                               // [2][64][68]
  const int tid = threadIdx.x;
  const int w = tid >> 6, lane = tid & 63;
  const int G = lane >> 4, lb = lane & 15;
  const int wk = w & 1, wq = w >> 1;
  const int qt = blockIdx.x, h = blockIdx.y, n = blockIdx.z;
  const int row = tid >> 3, c = (tid & 7) << 3;  // staging: 8 lanes/row

  // ---- Q fragments: global -> regs, once. q = 64wq+16nt+lb, d = 32ks+8G
  const short* Qb = Qg + ((size_t)(n * SL + (qt << 7) + 64 * wq)) * EMB + h * HD;
  bf16x8 bQ[4][2];
#pragma unroll
  for (int nt = 0; nt < 4; ++nt)
#pragma unroll
    for (int ks = 0; ks < 2; ++ks)
      bQ[nt][ks] =
          *(const bf16x8*)(Qb + (size_t)(16 * nt + lb) * EMB + 32 * ks + 8 * G);

  f32x4 O[4][4];  // [mtd: d=16mtd+4G+r][nt: q=64wq+16nt+lb]
  float lacc[4] = {0.f, 0.f, 0.f, 0.f};
#pragma unroll
  for (int i = 0; i < 4; ++i)
#pragma unroll
    for (int j = 0; j < 4; ++j) O[i][j] = (f32x4){0.f, 0.f, 0.f, 0.f};

  const short* Kb0 = Kg + ((size_t)(n * SL)) * EMB + h * HD;
  const short* Vb0 = Vtg + ((size_t)(n * NH + h)) * HD * SL;

  // prefetch tile 0 into registers (coalesced: 8 lanes x 128B per row)
  bf16x8 pk[2], pv[2];
#pragma unroll
  for (int k = 0; k < 2; ++k) {
    pk[k] = *(const bf16x8*)(Kb0 + (size_t)(row + 32 * k) * EMB + c);
    pv[k] = *(const bf16x8*)(Vb0 + (size_t)(row + 32 * k) * SL + c);
  }

  for (int kt = 0; kt < SL / 64; ++kt) {
    __syncthreads();  // previous iteration's LDS reads done
#pragma unroll
    for (int k = 0; k < 2; ++k) {
      *(bf16x8*)&Ks[row + 32 * k][c] = pk[k];
      *(bf16x8*)&Vt[row + 32 * k][c] = pv[k];
    }
    __syncthreads();
    if (kt + 1 < SL / 64) {  // issue next tile's loads; waited at next write
      const short* Kb = Kb0 + (size_t)(kt + 1) * 64 * EMB;
      const short* Vb = Vb0 + (size_t)(kt + 1) * 64;
#pragma unroll
      for (int k = 0; k < 2; ++k) {
        pk[k] = *(const bf16x8*)(Kb + (size_t)(row + 32 * k) * EMB + c);
        pv[k] = *(const bf16x8*)(Vb + (size_t)(row + 32 * k) * SL + c);
      }
    }

    // ---- S^T = K Q^T over this wave's 32-key half: keys 32wk+16mt+4G+r
    f32x4 S[2][4];
#pragma unroll
    for (int mt = 0; mt < 2; ++mt)
#pragma unroll
      for (int nt = 0; nt < 4; ++nt) S[mt][nt] = (f32x4){0.f, 0.f, 0.f, 0.f};
#pragma unroll
    for (int ks = 0; ks < 2; ++ks) {
      const bf16x8 aK0 = *(const bf16x8*)&Ks[32 * wk + lb][32 * ks + 8 * G];
      const bf16x8 aK1 = *(const bf16x8*)&Ks[32 * wk + 16 + lb][32 * ks + 8 * G];
#pragma unroll
      for (int nt = 0; nt < 4; ++nt) {
        S[0][nt] = __builtin_amdgcn_mfma_f32_16x16x32_bf16(aK0, bQ[nt][ks],
                                                           S[0][nt], 0, 0, 0);
        S[1][nt] = __builtin_amdgcn_mfma_f32_16x16x32_bf16(aK1, bQ[nt][ks],
                                                           S[1][nt], 0, 0, 0);
      }
    }

    // ---- P = exp2(S) in-regs; lane-local l (cross-lane deferred to end)
#pragma unroll
    for (int nt = 0; nt < 4; ++nt)
#pragma unroll
      for (int mt = 0; mt < 2; ++mt)
#pragma unroll
        for (int r = 0; r < 4; ++r) {
          const float p = __builtin_amdgcn_exp2f(S[mt][nt][r]);
          S[mt][nt][r] = p;
          lacc[nt] += p;
        }

    // ---- O^T += V_perm P : A = Vt cols [32wk..+32), B = P from C-regs
    bf16x8 aV[4];
#pragma unroll
    for (int mtd = 0; mtd < 4; ++mtd)
      aV[mtd] = *(const bf16x8*)&Vt[16 * mtd + lb][32 * wk + 8 * G];
#pragma unroll
    for (int nt = 0; nt < 4; ++nt) {
      bf16x8 B2;
      B2[0] = f2b(S[0][nt][0]);
      B2[1] = f2b(S[0][nt][1]);
      B2[2] = f2b(S[0][nt][2]);
      B2[3] = f2b(S[0][nt][3]);
      B2[4] = f2b(S[1][nt][0]);
      B2[5] = f2b(S[1][nt][1]);
      B2[6] = f2b(S[1][nt][2]);
      B2[7] = f2b(S[1][nt][3]);
#pragma unroll
      for (int mtd = 0; mtd < 4; ++mtd)
        O[mtd][nt] = __builtin_amdgcn_mfma_f32_16x16x32_bf16(aV[mtd], B2,
                                                             O[mtd][nt], 0, 0, 0);
    }
  }

  // ---- finish l: reduce across G groups (sum over this wave's 32 keys)
#pragma unroll
  for (int nt = 0; nt < 4; ++nt) {
    lacc[nt] += __shfl_xor(lacc[nt], 16);
    lacc[nt] += __shfl_xor(lacc[nt], 32);
  }

  // ---- 2-way cross-wave reduction over wk; red overlays staging LDS
  __syncthreads();
  if (wk == 1) {
#pragma unroll
    for (int nt = 0; nt < 4; ++nt) {
      const int q = 16 * nt + lb;
#pragma unroll
      for (int mtd = 0; mtd < 4; ++mtd)
        *(f32x4*)&red[wq * 4352 + q * 68 + 16 * mtd + 4 * G] = O[mtd][nt];
      if (G == 0) lred[wq * 64 + q] = lacc[nt];
    }
  }
  __syncthreads();
  if (wk == 0) {
    short* Ao = Ab + ((size_t)(n * SL + (qt << 7) + 64 * wq)) * EMB + h * HD;
#pragma unroll
    for (int nt = 0; nt < 4; ++nt) {
      const int q = 16 * nt + lb;
      const float inv = 1.f / (lacc[nt] + lred[wq * 64 + q]);
#pragma unroll
      for (int mtd = 0; mtd < 4; ++mtd) {
        const f32x4 t = *(const f32x4*)&red[wq * 4352 + q * 68 + 16 * mtd + 4 * G];
        const f32x4 s = t + O[mtd][nt];
        const short4 o = {f2b(s[0] * inv), f2b(s[1] * inv), f2b(s[2] * inv),
                          f2b(s[3] * inv)};
        *(short4*)(Ao + (size_t)q * EMB + 16 * mtd + 4 * G) = o;
      }
    }
  }
}

extern "C" void kernel_launch(void* const* d_in, const int* in_sizes, int n_in,
                              void* d_out, int out_size, void* d_ws, size_t ws_size,
                              hipStream_t stream) {
  const float* x  = (const float*)d_in[0];
  const float* Wq = (const float*)d_in[1];
  const float* Wk = (const float*)d_in[2];
  const float* Wv = (const float*)d_in[3];
  const float* Wo = (const float*)d_in[4];
  const float* bo = (const float*)d_in[5];
  float* out = (float*)d_out;

  // ws (bf16 elements): xb 4M | wqkv 3M | wob 1M | qb 4M | kb 4M | vt 4M = 40 MB
  short* xb   = (short*)d_ws;
  short* wqkv = xb + PROJ;
  short* wob  = wqkv + 3u * EMB * EMB;
  short* qb   = wob + (size_t)EMB * EMB;
  short* kb   = qb + PROJ;
  short* vt   = kb + PROJ;
  short* ab   = qb;  // alias: block-disjoint read-then-write regions

  cast_all<<<8192, 256, 0, stream>>>(x, Wq, Wk, Wv, Wo, xb, wqkv, wob);
  gemm_qkv<<<dim3(24, 32), 256, 0, stream>>>(xb, wqkv, qb, kb, vt);
  attn_mfma<<<dim3(SL / 128, NH, NB), 256, 0, stream>>>(qb, kb, vt, ab);
  gemm_out<<<dim3(16, 32), 256, 0, stream>>>(ab, wob, bo, out);
}

// Round 9
// 178.801 us; speedup vs baseline: 1.0431x; 1.0006x over previous
//
#include <hip/hip_runtime.h>
#include <hip/hip_bf16.h>

constexpr int NB  = 2;
constexpr int SL  = 2048;
constexpr int EMB = 1024;
constexpr int NH  = 16;
constexpr int HD  = 64;
constexpr int MT  = NB * SL;               // 4096 rows for projection GEMMs
constexpr size_t PROJ = (size_t)MT * EMB;  // 4M elements per [N,L,E] buffer

typedef __attribute__((ext_vector_type(8))) short bf16x8;  // 8 bf16 (4 VGPRs)
typedef __attribute__((ext_vector_type(4))) float f32x4;   // MFMA C/D frag

__device__ inline short f2b(float f) {
  __hip_bfloat16 b = __float2bfloat16(f);
  short s; __builtin_memcpy(&s, &b, 2); return s;
}

#define GLDS16(g, l)                                                     \
  __builtin_amdgcn_global_load_lds(                                      \
      (const __attribute__((address_space(1))) void*)(g),                \
      (__attribute__((address_space(3))) void*)(l), 16, 0, 0)

// ---------------------------------------------------------------------------
// Cast fp32 -> bf16: x -> xb, {Wq,Wk,Wv} -> wqkv (concat rows), Wo -> wob.
// ---------------------------------------------------------------------------
__global__ __launch_bounds__(256) void cast_all(
    const float* __restrict__ x,  const float* __restrict__ wq,
    const float* __restrict__ wk, const float* __restrict__ wv,
    const float* __restrict__ wo, short* __restrict__ xb,
    short* __restrict__ wqkv, short* __restrict__ wob) {
  const size_t t = (size_t)blockIdx.x * 256 + threadIdx.x;  // float4 index
  const float* src; short* dst; size_t base;
  if (t < 1048576)      { src = x;  dst = xb;              base = 0; }
  else if (t < 1310720) { src = wq; dst = wqkv;            base = 1048576; }
  else if (t < 1572864) { src = wk; dst = wqkv + (1 << 20); base = 1310720; }
  else if (t < 1835008) { src = wv; dst = wqkv + (2 << 20); base = 1572864; }
  else                  { src = wo; dst = wob;             base = 1835008; }
  const size_t i = t - base;
  const float4 v = ((const float4*)src)[i];
  const short4 o = {f2b(v.x), f2b(v.y), f2b(v.z), f2b(v.w)};
  ((short4*)dst)[i] = o;
}

// ---------------------------------------------------------------------------
// QKV GEMM (m97 recipe): C = x[4096][1024] @ wqkv[3072][1024]^T.
// 128x128 tile, BK=32, global_load_lds w16. Epilogue per n-region:
//   0 -> Q * (log2e/32)  (exp2 + score-scale folded)   bf16 natural
//   1 -> K                                             bf16 natural
//   2 -> V^T [nb][h][d][seq'] , seq' = 32-block key permutation
//        pos = 8*((k>>2)&3) + 4*(k>>4) + (k&3)  (attn PV A-frag order)
// ---------------------------------------------------------------------------
__global__ __launch_bounds__(256) void gemm_qkv(
    const short* __restrict__ A, const short* __restrict__ W,
    short* __restrict__ qb, short* __restrict__ kb, short* __restrict__ vt) {
  __shared__ short As[128 * 32];
  __shared__ short Bs[128 * 32];
  const int tid = threadIdx.x;
  const int w = tid >> 6, lane = tid & 63;
  const int la = lane >> 4, lb = lane & 15;
  const int wm = w & 1, wn = w >> 1;
  const int m0 = blockIdx.y << 7, n0 = blockIdx.x << 7;
  const int srow = lane >> 2, scol = (lane & 3) << 3;
  const short* a0 = A + (size_t)(m0 + w * 16 + srow) * 1024 + scol;
  const short* b0 = W + (size_t)(n0 + w * 16 + srow) * 1024 + scol;
  short* lA0 = As + (w * 16) * 32;
  short* lA1 = As + (64 + w * 16) * 32;
  short* lB0 = Bs + (w * 16) * 32;
  short* lB1 = Bs + (64 + w * 16) * 32;

  f32x4 acc[4][4];
#pragma unroll
  for (int i = 0; i < 4; ++i)
#pragma unroll
    for (int j = 0; j < 4; ++j) acc[i][j] = (f32x4){0.f, 0.f, 0.f, 0.f};

  for (int k0 = 0; k0 < 1024; k0 += 32) {
    __syncthreads();
    GLDS16(a0 + k0, lA0);
    GLDS16(a0 + 64 * 1024 + k0, lA1);
    GLDS16(b0 + k0, lB0);
    GLDS16(b0 + 64 * 1024 + k0, lB1);
    __syncthreads();
    bf16x8 af[4], bf[4];
#pragma unroll
    for (int i = 0; i < 4; ++i)
      af[i] = *(const bf16x8*)&As[(wm * 64 + i * 16 + lb) * 32 + la * 8];
#pragma unroll
    for (int j = 0; j < 4; ++j)
      bf[j] = *(const bf16x8*)&Bs[(wn * 64 + j * 16 + lb) * 32 + la * 8];
#pragma unroll
    for (int i = 0; i < 4; ++i)
#pragma unroll
      for (int j = 0; j < 4; ++j)
        acc[i][j] = __builtin_amdgcn_mfma_f32_16x16x32_bf16(af[i], bf[j],
                                                            acc[i][j], 0, 0, 0);
  }

  const int region = n0 >> 10;  // block-uniform (n-tile 128 < 1024)
  if (region < 2) {
    short* dst = region ? kb : qb;
    const float sc = region ? 1.0f : 0.03125f * 1.44269504f;  // Q: 1/32*log2e
    const int nb0 = n0 & 1023;
#pragma unroll
    for (int j = 0; j < 4; ++j) {
      const int nj = nb0 + wn * 64 + j * 16 + lb;
#pragma unroll
      for (int i = 0; i < 4; ++i) {
        const int mi = m0 + wm * 64 + i * 16 + la * 4;
#pragma unroll
        for (int r = 0; r < 4; ++r)
          dst[(size_t)(mi + r) * 1024 + nj] = f2b(acc[i][j][r] * sc);
      }
    }
  } else {
#pragma unroll
    for (int j = 0; j < 4; ++j) {
      const int nv = (n0 - 2048) + wn * 64 + j * 16 + lb;
      const int h = nv >> 6, d = nv & 63;
#pragma unroll
      for (int i = 0; i < 4; ++i) {
        const int mi = m0 + wm * 64 + i * 16 + la * 4;
        const int nbi = mi >> 11, seq = mi & (SL - 1);
        const int k5 = seq & 31;  // multiple of 4
        const int seqp = (seq & ~31) | (8 * ((k5 >> 2) & 3) + 4 * (k5 >> 4));
        const short4 o = {f2b(acc[i][j][0]), f2b(acc[i][j][1]),
                          f2b(acc[i][j][2]), f2b(acc[i][j][3])};
        *(short4*)&vt[((size_t)(nbi * NH + h) * HD + d) * SL + seqp] = o;
      }
    }
  }
}

// ---------------------------------------------------------------------------
// Out GEMM: out = ab[4096][1024](bf16) @ wob[1024][1024]^T + bias, fp32 out.
// 128m x 64n tile -> 512 blocks (2/CU) so barrier drains overlap.
// ---------------------------------------------------------------------------
__global__ __launch_bounds__(256) void gemm_out(
    const short* __restrict__ A, const short* __restrict__ W,
    const float* __restrict__ bias, float* __restrict__ out) {
  __shared__ short As[128 * 32];
  __shared__ short Bs[64 * 32];
  const int tid = threadIdx.x;
  const int w = tid >> 6, lane = tid & 63;
  const int la = lane >> 4, lb = lane & 15;
  const int wm = w & 1, wn = w >> 1;
  const int m0 = blockIdx.y << 7, n0 = blockIdx.x << 6;
  const int srow = lane >> 2, scol = (lane & 3) << 3;
  const short* a0 = A + (size_t)(m0 + w * 16 + srow) * 1024 + scol;
  const short* b0 = W + (size_t)(n0 + w * 16 + srow) * 1024 + scol;
  short* lA0 = As + (w * 16) * 32;
  short* lA1 = As + (64 + w * 16) * 32;
  short* lB0 = Bs + (w * 16) * 32;

  f32x4 acc[4][2];
#pragma unroll
  for (int i = 0; i < 4; ++i)
#pragma unroll
    for (int j = 0; j < 2; ++j) acc[i][j] = (f32x4){0.f, 0.f, 0.f, 0.f};

  for (int k0 = 0; k0 < 1024; k0 += 32) {
    __syncthreads();
    GLDS16(a0 + k0, lA0);
    GLDS16(a0 + 64 * 1024 + k0, lA1);
    GLDS16(b0 + k0, lB0);
    __syncthreads();
    bf16x8 af[4], bf[2];
#pragma unroll
    for (int i = 0; i < 4; ++i)
      af[i] = *(const bf16x8*)&As[(wm * 64 + i * 16 + lb) * 32 + la * 8];
#pragma unroll
    for (int j = 0; j < 2; ++j)
      bf[j] = *(const bf16x8*)&Bs[(wn * 32 + j * 16 + lb) * 32 + la * 8];
#pragma unroll
    for (int i = 0; i < 4; ++i)
#pragma unroll
      for (int j = 0; j < 2; ++j)
        acc[i][j] = __builtin_amdgcn_mfma_f32_16x16x32_bf16(af[i], bf[j],
                                                            acc[i][j], 0, 0, 0);
  }
#pragma unroll
  for (int j = 0; j < 2; ++j) {
    const int nj = n0 + wn * 32 + j * 16 + lb;
    const float bv = bias[nj];
#pragma unroll
    for (int i = 0; i < 4; ++i) {
      const int mi = m0 + wm * 64 + i * 16 + la * 4;
#pragma unroll
      for (int r = 0; r < 4; ++r)
        out[(size_t)(mi + r) * 1024 + nj] = acc[i][j][r] + bv;
    }
  }
}

// ---------------------------------------------------------------------------
// Flash attention v7 = R8 compute split + two stall fixes:
//  * KT=128 key-tiles, ping-pong LDS (2 x (K 128x72 + V 64x136) = 70 KB):
//    ONE barrier per iter (16 total vs 64). Per iter: write tile kt from
//    regs -> buf[kt&1]; barrier; issue tile kt+1's global loads (window =
//    full 2-sub-round compute ~1200cyc > 900cyc HBM latency); compute kt
//    as 2 sub-rounds of 32 keys/wave (S regs reused -> no VGPR growth).
//  * XCD-swizzled grid (h, qt, n): the 16 qt-blocks sharing one (h,n) K/V
//    slice get ids == h (mod 8) -> same XCD -> slice loads hit that XCD's
//    L2 (512 KB slice, 16x reuse) instead of re-fetching HBM per XCD.
//  * Rest identical to R8: 2x2 wave grid (wq=q-half, wk=key-half), Q
//    global->regs once, P=exp2(S) in C-regs -> PV B-operand, V pre-permuted
//    per 32-key block, deferred l shuffles, 2-way cross-wave O reduction.
// ---------------------------------------------------------------------------
__global__ __launch_bounds__(256, 2) void attn_mfma(const short* __restrict__ Qg,
                                                    const short* __restrict__ Kg,
                                                    const short* __restrict__ Vtg,
                                                    short* __restrict__ Ab) {
  __shared__ __align__(16) short smem[2 * 17920];  // buf: K 128*72 | V 64*136
  __shared__ float lred[128];
  const int tid = threadIdx.x;
  const int w = tid >> 6, lane = tid & 63;
  const int G = lane >> 4, lb = lane & 15;
  const int wk = w & 1, wq = w >> 1;
  const int h = blockIdx.x, qt = blockIdx.y, n = blockIdx.z;
  // staging geometry
  const int krow = tid >> 3, kcol = (tid & 7) << 3;    // K: 128r x 128B
  const int vrow = tid >> 4, vcol = (tid & 15) << 3;   // V: 64r x 256B

  // ---- Q fragments: global -> regs, once. q = 64wq+16nt+lb, d = 32ks+8G
  const short* Qb = Qg + ((size_t)(n * SL + (qt << 7) + 64 * wq)) * EMB + h * HD;
  bf16x8 bQ[4][2];
#pragma unroll
  for (int nt = 0; nt < 4; ++nt)
#pragma unroll
    for (int ks = 0; ks < 2; ++ks)
      bQ[nt][ks] =
          *(const bf16x8*)(Qb + (size_t)(16 * nt + lb) * EMB + 32 * ks + 8 * G);

  f32x4 O[4][4];  // [mtd: d=16mtd+4G+r][nt: q=64wq+16nt+lb]
  float lacc[4] = {0.f, 0.f, 0.f, 0.f};
#pragma unroll
  for (int i = 0; i < 4; ++i)
#pragma unroll
    for (int j = 0; j < 4; ++j) O[i][j] = (f32x4){0.f, 0.f, 0.f, 0.f};

  const short* Kb0 = Kg + ((size_t)(n * SL)) * EMB + h * HD;
  const short* Vb0 = Vtg + ((size_t)(n * NH + h)) * HD * SL;

  // preload tile 0 into registers (coalesced)
  bf16x8 pk[4], pv[4];
#pragma unroll
  for (int k = 0; k < 4; ++k)
    pk[k] = *(const bf16x8*)(Kb0 + (size_t)(krow + 32 * k) * EMB + kcol);
#pragma unroll
  for (int r = 0; r < 4; ++r)
    pv[r] = *(const bf16x8*)(Vb0 + (size_t)(vrow + 16 * r) * SL + vcol);

  for (int kt = 0; kt < SL / 128; ++kt) {
    short* Ks = &smem[(kt & 1) * 17920];
    short* Vt = Ks + 128 * 72;
    // ---- write tile kt (vmcnt wait on pk/pv happens here)
#pragma unroll
    for (int k = 0; k < 4; ++k)
      *(bf16x8*)&Ks[(krow + 32 * k) * 72 + kcol] = pk[k];
#pragma unroll
    for (int r = 0; r < 4; ++r)
      *(bf16x8*)&Vt[(vrow + 16 * r) * 136 + vcol] = pv[r];
    __syncthreads();  // single barrier: tile kt visible; prev buf reads done

    if (kt + 1 < SL / 128) {  // issue tile kt+1 loads; consumed next iter
      const short* Kb = Kb0 + (size_t)(kt + 1) * 128 * EMB;
#pragma unroll
      for (int k = 0; k < 4; ++k)
        pk[k] = *(const bf16x8*)(Kb + (size_t)(krow + 32 * k) * EMB + kcol);
#pragma unroll
      for (int r = 0; r < 4; ++r)
        pv[r] = *(const bf16x8*)(Vb0 + (size_t)(vrow + 16 * r) * SL +
                                 (kt + 1) * 128 + vcol);
    }

    // ---- two 32-key sub-rounds; wave wk owns keys [64wk+32s, +32)
#pragma unroll
    for (int s = 0; s < 2; ++s) {
      const int kb = 64 * wk + 32 * s;
      f32x4 S[2][4];
#pragma unroll
      for (int mt = 0; mt < 2; ++mt)
#pragma unroll
        for (int nt = 0; nt < 4; ++nt) S[mt][nt] = (f32x4){0.f, 0.f, 0.f, 0.f};
#pragma unroll
      for (int ks = 0; ks < 2; ++ks) {
        const bf16x8 aK0 = *(const bf16x8*)&Ks[(kb + lb) * 72 + 32 * ks + 8 * G];
        const bf16x8 aK1 =
            *(const bf16x8*)&Ks[(kb + 16 + lb) * 72 + 32 * ks + 8 * G];
#pragma unroll
        for (int nt = 0; nt < 4; ++nt) {
          S[0][nt] = __builtin_amdgcn_mfma_f32_16x16x32_bf16(aK0, bQ[nt][ks],
                                                             S[0][nt], 0, 0, 0);
          S[1][nt] = __builtin_amdgcn_mfma_f32_16x16x32_bf16(aK1, bQ[nt][ks],
                                                             S[1][nt], 0, 0, 0);
        }
      }

      // P = exp2(S) in-regs; lane-local l (cross-lane deferred to epilogue)
#pragma unroll
      for (int nt = 0; nt < 4; ++nt)
#pragma unroll
        for (int mt = 0; mt < 2; ++mt)
#pragma unroll
          for (int r = 0; r < 4; ++r) {
            const float p = __builtin_amdgcn_exp2f(S[mt][nt][r]);
            S[mt][nt][r] = p;
            lacc[nt] += p;
          }

      // O^T += V_perm P : A = Vt cols [kb, +32), B = P from C-regs
      bf16x8 aV[4];
#pragma unroll
      for (int mtd = 0; mtd < 4; ++mtd)
        aV[mtd] = *(const bf16x8*)&Vt[(16 * mtd + lb) * 136 + kb + 8 * G];
#pragma unroll
      for (int nt = 0; nt < 4; ++nt) {
        bf16x8 B2;
        B2[0] = f2b(S[0][nt][0]);
        B2[1] = f2b(S[0][nt][1]);
        B2[2] = f2b(S[0][nt][2]);
        B2[3] = f2b(S[0][nt][3]);
        B2[4] = f2b(S[1][nt][0]);
        B2[5] = f2b(S[1][nt][1]);
        B2[6] = f2b(S[1][nt][2]);
        B2[7] = f2b(S[1][nt][3]);
#pragma unroll
        for (int mtd = 0; mtd < 4; ++mtd)
          O[mtd][nt] = __builtin_amdgcn_mfma_f32_16x16x32_bf16(aV[mtd], B2,
                                                               O[mtd][nt], 0, 0, 0);
      }
    }
  }

  // ---- finish l: reduce across G groups (sum over this wave's keys)
#pragma unroll
  for (int nt = 0; nt < 4; ++nt) {
    lacc[nt] += __shfl_xor(lacc[nt], 16);
    lacc[nt] += __shfl_xor(lacc[nt], 32);
  }

  // ---- 2-way cross-wave reduction over wk; red overlays staging LDS
  float* red = (float*)smem;  // [2][64][68] f32 = 34.8 KB
  __syncthreads();
  if (wk == 1) {
#pragma unroll
    for (int nt = 0; nt < 4; ++nt) {
      const int q = 16 * nt + lb;
#pragma unroll
      for (int mtd = 0; mtd < 4; ++mtd)
        *(f32x4*)&red[wq * 4352 + q * 68 + 16 * mtd + 4 * G] = O[mtd][nt];
      if (G == 0) lred[wq * 64 + q] = lacc[nt];
    }
  }
  __syncthreads();
  if (wk == 0) {
    short* Ao = Ab + ((size_t)(n * SL + (qt << 7) + 64 * wq)) * EMB + h * HD;
#pragma unroll
    for (int nt = 0; nt < 4; ++nt) {
      const int q = 16 * nt + lb;
      const float inv = 1.f / (lacc[nt] + lred[wq * 64 + q]);
#pragma unroll
      for (int mtd = 0; mtd < 4; ++mtd) {
        const f32x4 t = *(const f32x4*)&red[wq * 4352 + q * 68 + 16 * mtd + 4 * G];
        const f32x4 s = t + O[mtd][nt];
        const short4 o = {f2b(s[0] * inv), f2b(s[1] * inv), f2b(s[2] * inv),
                          f2b(s[3] * inv)};
        *(short4*)(Ao + (size_t)q * EMB + 16 * mtd + 4 * G) = o;
      }
    }
  }
}

extern "C" void kernel_launch(void* const* d_in, const int* in_sizes, int n_in,
                              void* d_out, int out_size, void* d_ws, size_t ws_size,
                              hipStream_t stream) {
  const float* x  = (const float*)d_in[0];
  const float* Wq = (const float*)d_in[1];
  const float* Wk = (const float*)d_in[2];
  const float* Wv = (const float*)d_in[3];
  const float* Wo = (const float*)d_in[4];
  const float* bo = (const float*)d_in[5];
  float* out = (float*)d_out;

  // ws (bf16 elements): xb 4M | wqkv 3M | wob 1M | qb 4M | kb 4M | vt 4M = 40 MB
  short* xb   = (short*)d_ws;
  short* wqkv = xb + PROJ;
  short* wob  = wqkv + 3u * EMB * EMB;
  short* qb   = wob + (size_t)EMB * EMB;
  short* kb   = qb + PROJ;
  short* vt   = kb + PROJ;
  short* ab   = qb;  // alias: block-disjoint read-then-write regions

  cast_all<<<8192, 256, 0, stream>>>(x, Wq, Wk, Wv, Wo, xb, wqkv, wob);
  gemm_qkv<<<dim3(24, 32), 256, 0, stream>>>(xb, wqkv, qb, kb, vt);
  attn_mfma<<<dim3(NH, SL / 128, NB), 256, 0, stream>>>(qb, kb, vt, ab);
  gemm_out<<<dim3(16, 32), 256, 0, stream>>>(ab, wob, bo, out);
}